// Round 12
// baseline (883.061 us; speedup 1.0000x reference)
//
#include <hip/hip_runtime.h>
#include <hip/hip_bf16.h>
#include <cstdint>

// ---------------------------------------------------------------------------
// ThreeLayerCNN (BranchyNet early-exit), B=4096.
// Precision: conv1/conv2/exit1/exit2 fp32 (argmax parity with numpy ref);
// big FC GEMMs (l1c1, l1c2) bf16 MFMA w/ fp32 accum (output tol 0.146).
// Round 12: conv2 role rebuilt = r7 scalar-weight layout (block=2 img,
// lane=img*pos, wave=13-oc slice, weights via wave-uniform s_load — zero
// LDS/VMEM vector cost) + r11 chunked dbuf input staging (10.9 KB LDS).
// In the fused k_stage1 (15.4 KB dyn LDS) this gets the 5-6 blocks/CU that
// r7 lacked. conv2 LDS-unit load drops 273->93 cyc/wave-ic -> VALU-bound.
// FP tree identical to r7 (passed). Everything else = round 11.
// ---------------------------------------------------------------------------

typedef __bf16 bf16_t;
typedef __bf16 bf16x8 __attribute__((ext_vector_type(8)));
typedef float  f32x4  __attribute__((ext_vector_type(4)));

#define B_IMG 4096

// ======================= role bodies (device functions) =====================

__device__ void role_conv1(char* smem, int blk,
    const float* __restrict__ x, const float* __restrict__ w1,
    const float* __restrict__ b1, float* __restrict__ h1)
{
    float* ws = (float*)smem;        // 450
    float* bs = ws + 456;            // 50
    const int t = threadIdx.x;
    for (int i = t; i < 450; i += 256) ws[i] = w1[i];
    if (t < 50) bs[t] = b1[t];
    __syncthreads();

    const int idx = blk * 256 + t;
    if (idx >= B_IMG * 169) return;
    const int b   = idx / 169;
    const int pos = idx % 169;
    const int py = pos / 13, px = pos % 13;

    const float* xp = x + (size_t)b * 784 + (2 * py) * 28 + 2 * px;
    float p[4][4];
#pragma unroll
    for (int r = 0; r < 4; ++r)
#pragma unroll
        for (int c = 0; c < 4; ++c) p[r][c] = xp[r * 28 + c];

    float* hb = h1 + (size_t)b * 8480 + pos;
    if (pos < 30) h1[(size_t)b * 8480 + 8450 + pos] = 0.f;   // zero pad cols

    for (int oc = 0; oc < 50; ++oc) {
        const float* wp = &ws[oc * 9];
        const float w00 = wp[0], w01 = wp[1], w02 = wp[2];
        const float w10 = wp[3], w11 = wp[4], w12 = wp[5];
        const float w20 = wp[6], w21 = wp[7], w22 = wp[8];
        float a[2][2];
#pragma unroll
        for (int dy = 0; dy < 2; ++dy)
#pragma unroll
            for (int dx = 0; dx < 2; ++dx) {
                a[dy][dx] = p[dy + 0][dx + 0] * w00 + p[dy + 0][dx + 1] * w01 + p[dy + 0][dx + 2] * w02
                          + p[dy + 1][dx + 0] * w10 + p[dy + 1][dx + 1] * w11 + p[dy + 1][dx + 2] * w12
                          + p[dy + 2][dx + 0] * w20 + p[dy + 2][dx + 1] * w21 + p[dy + 2][dx + 2] * w22;
            }
        float v = fmaxf(fmaxf(a[0][0], a[0][1]), fmaxf(a[1][0], a[1][1])) + bs[oc];
        hb[oc * 169] = fmaxf(v, 0.f);
    }
}

__device__ void role_wb16(int blk, const float* __restrict__ src,
                          bf16_t* __restrict__ dst, int N, int K, int Kp, int total)
{
    const int idx = blk * 256 + threadIdx.x;
    if (idx >= total) return;
    const int n = idx / Kp, k = idx % Kp;
    const float v = (n < N && k < K) ? src[(size_t)n * K + k] : 0.f;
    dst[idx] = (bf16_t)v;
}

// conv2 (50->50) + relu + pool. Block = 2 images, 256 thr = 4 waves.
// lane=(img,pos) (50/64 active); wave w -> ocs 13/13/12/12, wave-uniform ->
// weights via scalar s_load from global w2 (L2-resident, 90 KB). Input in
// LDS 4-ic double-buffered chunks: [buf][img][680] = 10880 B total.
// FP expression tree identical to r7/r2/r4 (exit2 argmax parity).
__device__ void role_conv2(char* smem, int blk,
    const float* __restrict__ h1, const float* __restrict__ w2,
    const float* __restrict__ b2, float* __restrict__ h2)
{
    float* in = (float*)smem;     // buf*1360 + img*680 + idx  (2720 floats)
    const int t  = threadIdx.x;
    const int b0 = blk * 2;

    // stage chunk 0 (ic 0..3) for both images
#pragma unroll
    for (int img = 0; img < 2; ++img)
        for (int s = t; s < 676; s += 256)
            in[img * 680 + s] = h1[(size_t)(b0 + img) * 8480 + s];
    __syncthreads();
    if (t < 60) h2[(size_t)(b0 + t / 30) * 1280 + 1250 + (t % 30)] = 0.f;

    const int lane = t & 63;
    const int wv   = t >> 6;
    const int oc0  = __builtin_amdgcn_readfirstlane((wv < 2) ? wv * 13 : 26 + (wv - 2) * 12);
    const int noc  = __builtin_amdgcn_readfirstlane(13 - (wv >> 1));   // 13,13,12,12

    const bool act = (lane < 50);
    const int img2 = act ? (lane / 25) : 0;
    const int pos  = act ? (lane % 25) : 0;
    const int py = pos / 5, px = pos % 5;
    const int pofs = img2 * 680 + (2 * py) * 13 + 2 * px;

    float acc[13][4];
#pragma unroll
    for (int j = 0; j < 13; ++j)
#pragma unroll
        for (int q = 0; q < 4; ++q) acc[j][q] = 0.f;

#pragma unroll 1
    for (int ic0 = 0; ic0 < 50; ic0 += 4) {
        const int cur = (ic0 >> 2) & 1;
        if (ic0 + 4 < 50) {      // prefetch next <=4-ic input chunk
            const int nxt = cur ^ 1;
            const int nic2 = (50 - ic0 - 4 < 4) ? (50 - ic0 - 4) : 4;
#pragma unroll
            for (int img = 0; img < 2; ++img)
                for (int s = t; s < nic2 * 169; s += 256)
                    in[nxt * 1360 + img * 680 + s] =
                        h1[(size_t)(b0 + img) * 8480 + (ic0 + 4) * 169 + s];
        }
        const int nic = (50 - ic0 < 4) ? (50 - ic0) : 4;
        if (act) {
#pragma unroll
            for (int icl = 0; icl < 4; ++icl) {
                if (icl < nic) {
                    const int ic = ic0 + icl;
                    const float* ip = in + cur * 1360 + pofs + icl * 169;
                    float p[4][4];
#pragma unroll
                    for (int r = 0; r < 4; ++r)
#pragma unroll
                        for (int c = 0; c < 4; ++c) p[r][c] = ip[r * 13 + c];

                    const float* wic = w2 + (size_t)oc0 * 450 + ic * 9;
#pragma unroll
                    for (int j = 0; j < 13; ++j) {
                        if (j < noc) {
                            const float* wp = wic + j * 450;
                            const float w00 = wp[0], w01 = wp[1], w02 = wp[2];
                            const float w10 = wp[3], w11 = wp[4], w12 = wp[5];
                            const float w20 = wp[6], w21 = wp[7], w22 = wp[8];
#pragma unroll
                            for (int dy = 0; dy < 2; ++dy)
#pragma unroll
                                for (int dx = 0; dx < 2; ++dx) {
                                    acc[j][dy * 2 + dx] +=
                                          p[dy + 0][dx + 0] * w00 + p[dy + 0][dx + 1] * w01 + p[dy + 0][dx + 2] * w02
                                        + p[dy + 1][dx + 0] * w10 + p[dy + 1][dx + 1] * w11 + p[dy + 1][dx + 2] * w12
                                        + p[dy + 2][dx + 0] * w20 + p[dy + 2][dx + 1] * w21 + p[dy + 2][dx + 2] * w22;
                                }
                        }
                    }
                }
            }
        }
        __syncthreads();
    }

    if (act) {
#pragma unroll
        for (int j = 0; j < 13; ++j) {
            if (j < noc) {
                float v = fmaxf(fmaxf(acc[j][0], acc[j][1]), fmaxf(acc[j][2], acc[j][3]));
                v = fmaxf(v + b2[oc0 + j], 0.f);
                h2[(size_t)(b0 + img2) * 1280 + (oc0 + j) * 25 + pos] = v;
            }
        }
    }
}

__device__ void role_conv3(char* smem, int blk,
    const float* __restrict__ h2, const float* __restrict__ w3,
    const float* __restrict__ b3, float* __restrict__ f3)
{
    float* in = (float*)smem;    // 5000
    const int t = threadIdx.x;
    for (int i = t; i < 5000; i += 256) {
        const int img = i / 1250, off = i % 1250;
        in[i] = h2[(size_t)(blk * 4 + img) * 1280 + off];
    }
    __syncthreads();
    const int il = t >> 6;
    const int oc = t & 63;
    if (oc >= 50) return;

    const float* ip0 = &in[il * 1250];
    float a00 = 0.f, a01 = 0.f, a10 = 0.f, a11 = 0.f;
    for (int ic = 0; ic < 50; ++ic) {
        float p[4][4];
        const float* ip = ip0 + ic * 25;
#pragma unroll
        for (int r = 0; r < 4; ++r)
#pragma unroll
            for (int c = 0; c < 4; ++c) p[r][c] = ip[r * 5 + c];
        const float* wp = &w3[((size_t)oc * 50 + ic) * 9];
        const float w00 = wp[0], w01 = wp[1], w02 = wp[2];
        const float w10 = wp[3], w11 = wp[4], w12 = wp[5];
        const float w20 = wp[6], w21 = wp[7], w22 = wp[8];
        a00 += p[0][0]*w00 + p[0][1]*w01 + p[0][2]*w02 + p[1][0]*w10 + p[1][1]*w11 + p[1][2]*w12 + p[2][0]*w20 + p[2][1]*w21 + p[2][2]*w22;
        a01 += p[0][1]*w00 + p[0][2]*w01 + p[0][3]*w02 + p[1][1]*w10 + p[1][2]*w11 + p[1][3]*w12 + p[2][1]*w20 + p[2][2]*w21 + p[2][3]*w22;
        a10 += p[1][0]*w00 + p[1][1]*w01 + p[1][2]*w02 + p[2][0]*w10 + p[2][1]*w11 + p[2][2]*w12 + p[3][0]*w20 + p[3][1]*w21 + p[3][2]*w22;
        a11 += p[1][1]*w00 + p[1][2]*w01 + p[1][3]*w02 + p[2][1]*w10 + p[2][2]*w11 + p[2][3]*w12 + p[3][1]*w20 + p[3][2]*w21 + p[3][3]*w22;
    }
    float v = fmaxf(fmaxf(a00, a01), fmaxf(a10, a11)) + b3[oc];
    f3[(size_t)(blk * 4 + il) * 50 + oc] = fmaxf(v, 0.f);
}

__device__ void role_exit(char* smem, int b,
    const float* __restrict__ F, int ldf, int K,
    const float* __restrict__ dw, const float* __restrict__ db, int* __restrict__ e)
{
    float* r0 = (float*)smem;   // 256
    float* r1 = r0 + 256;       // 256
    const int t = threadIdx.x;
    const float* f = F + (size_t)b * ldf;
    float s0 = 0.f, s1 = 0.f;
    for (int i = t; i < K; i += 256) {
        const float v = f[i];
        s0 += v * dw[i];
        s1 += v * dw[K + i];
    }
    r0[t] = s0; r1[t] = s1;
    __syncthreads();
    for (int s = 128; s > 0; s >>= 1) {
        if (t < s) { r0[t] += r0[t + s]; r1[t] += r1[t + s]; }
        __syncthreads();
    }
    if (t == 0) e[b] = (r0[0] + db[0] >= r1[0] + db[1]) ? 1 : 0;
}

// MFMA GEMM split-K=2 (r9-proven). g in [0,512): bx=g&31, by=(g>>5)&7, kz=g>>8.
__device__ void role_gemm(char* smem, int g,
    const float* __restrict__ A, int lda, const bf16_t* __restrict__ W,
    const float* __restrict__ bias, float* __restrict__ C0, float* __restrict__ C1,
    int Kp, int khalf, int Nout, int ldc)
{
    bf16_t* As = (bf16_t*)smem;      // 128*40
    bf16_t* Bs = As + 128 * 40;      // 64*40

    const int t = threadIdx.x;
    const int m0 = (g & 31) * 128;
    const int n0 = ((g >> 5) & 7) * 64;
    const int kz = g >> 8;
    const int kbeg = kz ? khalf : 0;
    const int kend = kz ? Kp : khalf;
    float* C = kz ? C1 : C0;

    const int wave = t >> 6;
    const int lane = t & 63;
    const int wm = (wave >> 1) * 64;
    const int wn = (wave & 1) * 32;
    const int quad = lane >> 4;
    const int lr = lane & 15;

    f32x4 acc[4][2];
#pragma unroll
    for (int i = 0; i < 4; ++i)
#pragma unroll
        for (int j = 0; j < 2; ++j) acc[i][j] = (f32x4)0.f;

    const int ar = t >> 2;
    const int ac = (t & 3) * 8;

    for (int k0 = kbeg; k0 < kend; k0 += 32) {
        __syncthreads();
#pragma unroll
        for (int h = 0; h < 2; ++h) {
            const float* ap = A + (size_t)(m0 + ar + h * 64) * lda + k0 + ac;
            const float4 f0 = *(const float4*)ap;
            const float4 f1 = *(const float4*)(ap + 4);
            bf16x8 v;
            v[0] = (bf16_t)f0.x; v[1] = (bf16_t)f0.y; v[2] = (bf16_t)f0.z; v[3] = (bf16_t)f0.w;
            v[4] = (bf16_t)f1.x; v[5] = (bf16_t)f1.y; v[6] = (bf16_t)f1.z; v[7] = (bf16_t)f1.w;
            *(bf16x8*)&As[(ar + h * 64) * 40 + ac] = v;
        }
        *(uint4*)&Bs[ar * 40 + ac] = *(const uint4*)&W[(size_t)(n0 + ar) * Kp + k0 + ac];
        __syncthreads();

        bf16x8 af[4], bfr[2];
#pragma unroll
        for (int i = 0; i < 4; ++i)
            af[i] = *(const bf16x8*)&As[(wm + i * 16 + lr) * 40 + quad * 8];
#pragma unroll
        for (int j = 0; j < 2; ++j)
            bfr[j] = *(const bf16x8*)&Bs[(wn + j * 16 + lr) * 40 + quad * 8];
#pragma unroll
        for (int i = 0; i < 4; ++i)
#pragma unroll
            for (int j = 0; j < 2; ++j)
                acc[i][j] = __builtin_amdgcn_mfma_f32_16x16x32_bf16(af[i], bfr[j], acc[i][j], 0, 0, 0);
    }

#pragma unroll
    for (int j = 0; j < 2; ++j) {
        const int n = n0 + wn + j * 16 + lr;
        const float bv = (kz == 0 && n < Nout) ? bias[n] : 0.f;
#pragma unroll
        for (int i = 0; i < 4; ++i) {
            const int mrow = m0 + wm + i * 16 + quad * 4;
#pragma unroll
            for (int r = 0; r < 4; ++r)
                C[(size_t)(mrow + r) * ldc + n] = acc[i][j][r] + bv;
        }
    }
}

// lin10: out[b,o<10] = (U[+U2]) @ W^T + bias; 16 img x 16 k-strips per block.
__device__ void role_lin10(char* smem, int blk,
    const float* __restrict__ U, const float* __restrict__ U2, int ldu,
    const float* __restrict__ W, const float* __restrict__ bias,
    float* __restrict__ out)
{
    float* red = (float*)smem;   // [16][10][17]
    const int t = threadIdx.x;
    const int ks = t & 15;
    const int il = t >> 4;
    const int b  = blk * 16 + il;
    const float* u = U + (size_t)b * ldu;

    float acc[10];
#pragma unroll
    for (int o = 0; o < 10; ++o) acc[o] = 0.f;

    if (U2) {
        const float* u2 = U2 + (size_t)b * ldu;
        for (int i = 0; i < 31; ++i) {
            const int k = ks + i * 16;
            const float uv = u[k] + u2[k];
#pragma unroll
            for (int o = 0; o < 10; ++o) acc[o] += uv * W[o * 500 + k];
        }
        const int k = ks + 496;
        if (k < 500) {
            const float uv = u[k] + u2[k];
#pragma unroll
            for (int o = 0; o < 10; ++o) acc[o] += uv * W[o * 500 + k];
        }
    } else {
        for (int i = 0; i < 31; ++i) {
            const int k = ks + i * 16;
            const float uv = u[k];
#pragma unroll
            for (int o = 0; o < 10; ++o) acc[o] += uv * W[o * 500 + k];
        }
        const int k = ks + 496;
        if (k < 500) {
            const float uv = u[k];
#pragma unroll
            for (int o = 0; o < 10; ++o) acc[o] += uv * W[o * 500 + k];
        }
    }
#pragma unroll
    for (int o = 0; o < 10; ++o) red[(il * 10 + o) * 17 + ks] = acc[o];
    __syncthreads();
    if (t < 160) {
        const int il2 = t / 10, o = t - il2 * 10;
        float s = 0.f;
#pragma unroll
        for (int q = 0; q < 16; ++q) s += red[(il2 * 10 + o) * 17 + q];
        out[(size_t)(blk * 16 + il2) * 10 + o] = s + bias[o];
    }
}

// ============================ fused kernels ================================

__global__ __launch_bounds__(256) void k_prep(
    const float* x, const float* c1w, const float* c1b, float* h1,
    const float* l1c1w, bf16_t* Wb1, const float* l1c2w, bf16_t* Wb2)
{
    extern __shared__ char smem[];
    const int g = blockIdx.x;
    if (g < 2704)        role_conv1(smem, g, x, c1w, c1b, h1);
    else if (g < 19664)  role_wb16(g - 2704, l1c1w, Wb1, 500, 8450, 8480, 512 * 8480);
    else                 role_wb16(g - 19664, l1c2w, Wb2, 500, 1250, 1280, 512 * 1280);
}

__global__ __launch_bounds__(256) void k_stage1(
    const float* h1, const bf16_t* Wb1, const float* l1c1b, float* u, float* up,
    const float* d1w, const float* d1b, int* e1,
    const float* c2w, const float* c2b, float* h2)
{
    extern __shared__ char smem[];
    const int g = blockIdx.x;
    if (g < 512)         role_gemm(smem, g, h1, 8480, Wb1, l1c1b, u, up, 8480, 4256, 500, 512);
    else if (g < 2560)   role_conv2(smem, g - 512, h1, c2w, c2b, h2);
    else                 role_exit(smem, g - 2560, h1, 8480, 8450, d1w, d1b, e1);
}

__global__ __launch_bounds__(256) void k_stage2(
    const float* h2, const bf16_t* Wb2, const float* l1c2b, float* v, float* vp,
    const float* d2w, const float* d2b, int* e2,
    const float* c3w, const float* c3b, float* f3,
    const float* u, const float* up, const float* l2c1w, const float* l2c1b, float* out1)
{
    extern __shared__ char smem[];
    const int g = blockIdx.x;
    if (g < 512)         role_gemm(smem, g, h2, 1280, Wb2, l1c2b, v, vp, 1280, 640, 500, 512);
    else if (g < 1536)   role_conv3(smem, g - 512, h2, c3w, c3b, f3);
    else if (g < 1792)   role_lin10(smem, g - 1536, u, up, 512, l2c1w, l2c1b, out1);
    else                 role_exit(smem, g - 1792, h2, 1280, 1250, d2w, d2b, e2);
}

// k_tail: per block = 16 samples. lin10-2 (v/vp) -> o2loc; lin500 -> u3 LDS;
// lin10-3 (u3 LDS) -> o3loc; select + log_softmax -> out.
__global__ __launch_bounds__(256) void k_tail(
    const float* __restrict__ v, const float* __restrict__ vp,
    const float* __restrict__ l2c2w, const float* __restrict__ l2c2b,
    const float* __restrict__ f3, const float* __restrict__ l1w, const float* __restrict__ l1b,
    const float* __restrict__ l2w, const float* __restrict__ l2b,
    const float* __restrict__ out1, const int* __restrict__ e1, const int* __restrict__ e2,
    float* __restrict__ out)
{
    __shared__ float fs[800];        // 16 x 50
    __shared__ float u3loc[8000];    // 16 x 500
    __shared__ float red[2720];      // 16 x 10 x 17
    __shared__ float o2loc[160];
    __shared__ float o3loc[160];

    const int t   = threadIdx.x;
    const int blk = blockIdx.x;
    const int ks  = t & 15;
    const int il  = t >> 4;

    for (int i = t; i < 800; i += 256) fs[i] = f3[(size_t)blk * 800 + i];
    __syncthreads();

    for (int im = 0; im < 16; ++im) {
        for (int o = t; o < 500; o += 256) {
            float s = 0.f;
#pragma unroll
            for (int k = 0; k < 50; ++k) s += fs[im * 50 + k] * l1w[o * 50 + k];
            u3loc[im * 500 + o] = fmaxf(s + l1b[o], 0.f);
        }
    }

    {
        const float* uu  = v  + (size_t)(blk * 16 + il) * 512;
        const float* uu2 = vp + (size_t)(blk * 16 + il) * 512;
        float acc[10];
#pragma unroll
        for (int o = 0; o < 10; ++o) acc[o] = 0.f;
        for (int i = 0; i < 31; ++i) {
            const int k = ks + i * 16;
            const float uv = uu[k] + uu2[k];
#pragma unroll
            for (int o = 0; o < 10; ++o) acc[o] += uv * l2c2w[o * 500 + k];
        }
        const int k = ks + 496;
        if (k < 500) {
            const float uv = uu[k] + uu2[k];
#pragma unroll
            for (int o = 0; o < 10; ++o) acc[o] += uv * l2c2w[o * 500 + k];
        }
        __syncthreads();
#pragma unroll
        for (int o = 0; o < 10; ++o) red[(il * 10 + o) * 17 + ks] = acc[o];
        __syncthreads();
        if (t < 160) {
            const int il2 = t / 10, o = t - il2 * 10;
            float s = 0.f;
#pragma unroll
            for (int q = 0; q < 16; ++q) s += red[(il2 * 10 + o) * 17 + q];
            o2loc[t] = s + l2c2b[o];
        }
        __syncthreads();
    }

    {
        const float* uu = u3loc + il * 500;
        float acc[10];
#pragma unroll
        for (int o = 0; o < 10; ++o) acc[o] = 0.f;
        for (int i = 0; i < 31; ++i) {
            const int k = ks + i * 16;
            const float uv = uu[k];
#pragma unroll
            for (int o = 0; o < 10; ++o) acc[o] += uv * l2w[o * 500 + k];
        }
        const int k = ks + 496;
        if (k < 500) {
            const float uv = uu[k];
#pragma unroll
            for (int o = 0; o < 10; ++o) acc[o] += uv * l2w[o * 500 + k];
        }
#pragma unroll
        for (int o = 0; o < 10; ++o) red[(il * 10 + o) * 17 + ks] = acc[o];
        __syncthreads();
        if (t < 160) {
            const int il2 = t / 10, o = t - il2 * 10;
            float s = 0.f;
#pragma unroll
            for (int q = 0; q < 16; ++q) s += red[(il2 * 10 + o) * 17 + q];
            o3loc[t] = s + l2b[o];
        }
        __syncthreads();
    }

    if (t < 16) {
        const int b = blk * 16 + t;
        float vv[10];
        if (e1[b]) {
            const float* src = out1 + (size_t)b * 10;
#pragma unroll
            for (int o = 0; o < 10; ++o) vv[o] = src[o];
        } else if (e2[b]) {
#pragma unroll
            for (int o = 0; o < 10; ++o) vv[o] = o2loc[t * 10 + o];
        } else {
#pragma unroll
            for (int o = 0; o < 10; ++o) vv[o] = o3loc[t * 10 + o];
        }
        float m = -3.4e38f;
#pragma unroll
        for (int o = 0; o < 10; ++o) m = fmaxf(m, vv[o]);
        float s = 0.f;
#pragma unroll
        for (int o = 0; o < 10; ++o) s += expf(vv[o] - m);
        const float ls = logf(s);
#pragma unroll
        for (int o = 0; o < 10; ++o) out[(size_t)b * 10 + o] = vv[o] - m - ls;
    }
}

// ---------------------------------------------------------------------------
static inline size_t align256(size_t v) { return (v + 255) & ~(size_t)255; }

extern "C" void kernel_launch(void* const* d_in, const int* in_sizes, int n_in,
                              void* d_out, int out_size, void* d_ws, size_t ws_size,
                              hipStream_t stream)
{
    const float* x     = (const float*)d_in[0];
    const float* c1w   = (const float*)d_in[1];
    const float* c1b   = (const float*)d_in[2];
    const float* c2w   = (const float*)d_in[3];
    const float* c2b   = (const float*)d_in[4];
    const float* c3w   = (const float*)d_in[5];
    const float* c3b   = (const float*)d_in[6];
    const float* l1c1w = (const float*)d_in[7];
    const float* l1c1b = (const float*)d_in[8];
    const float* l2c1w = (const float*)d_in[9];
    const float* l2c1b = (const float*)d_in[10];
    const float* l1c2w = (const float*)d_in[11];
    const float* l1c2b = (const float*)d_in[12];
    const float* l2c2w = (const float*)d_in[13];
    const float* l2c2b = (const float*)d_in[14];
    const float* l1w   = (const float*)d_in[15];
    const float* l1b   = (const float*)d_in[16];
    const float* l2w   = (const float*)d_in[17];
    const float* l2b   = (const float*)d_in[18];
    const float* d1w   = (const float*)d_in[19];
    const float* d1b   = (const float*)d_in[20];
    const float* d2w   = (const float*)d_in[21];
    const float* d2b   = (const float*)d_in[22];

    // ---- workspace layout (single chunk, B=4096) ----
    size_t off = 0;
    const size_t oWb1  = off; off = align256(off + (size_t)512 * 8480 * 2);
    const size_t oWb2  = off; off = align256(off + (size_t)512 * 1280 * 2);
    const size_t oOut1 = off; off = align256(off + (size_t)B_IMG * 10 * 4);
    const size_t oE1   = off; off = align256(off + (size_t)B_IMG * 4);
    const size_t oE2   = off; off = align256(off + (size_t)B_IMG * 4);
    const size_t oH1   = off; off = align256(off + (size_t)B_IMG * 8480 * 4);
    const size_t oH2   = off; off = align256(off + (size_t)B_IMG * 1280 * 4);
    const size_t oU    = off; off = align256(off + (size_t)B_IMG * 512 * 4);
    const size_t oUP   = off; off = align256(off + (size_t)B_IMG * 512 * 4);
    const size_t oF3   = off; off = align256(off + (size_t)B_IMG * 50 * 4);

    char* ws = (char*)d_ws;
    bf16_t* Wb1  = (bf16_t*)(ws + oWb1);
    bf16_t* Wb2  = (bf16_t*)(ws + oWb2);
    float*  out1 = (float*) (ws + oOut1);
    int*    e1   = (int*)   (ws + oE1);
    int*    e2   = (int*)   (ws + oE2);
    float*  h1   = (float*) (ws + oH1);
    float*  h2   = (float*) (ws + oH2);
    float*  u    = (float*) (ws + oU);
    float*  up   = (float*) (ws + oUP);
    float*  f3   = (float*) (ws + oF3);
    // stage-2 gemm outputs carved from the dead h1 region
    float*  v    = h1;                          // 4096*512 f32
    float*  vp   = h1 + (size_t)B_IMG * 512;    // 4096*512 f32

    float* out = (float*)d_out;

    // P: conv1 + weight conversions
    k_prep<<<22224, 256, 2048, stream>>>(x, c1w, c1b, h1, l1c1w, Wb1, l1c2w, Wb2);
    // A: gemm1 | conv2(scalar-weight, 2 img/block) | exit1 ; 15360 B dyn LDS
    k_stage1<<<6656, 256, 15360, stream>>>(h1, Wb1, l1c1b, u, up, d1w, d1b, e1, c2w, c2b, h2);
    // C: gemm2 | conv3 | lin10-1 | exit2
    k_stage2<<<5888, 256, 20000, stream>>>(h2, Wb2, l1c2b, v, vp, d2w, d2b, e2,
                                           c3w, c3b, f3, u, up, l2c1w, l2c1b, out1);
    // T: lin10-2 | lin500 | lin10-3 | select
    k_tail<<<256, 256, 0, stream>>>(v, vp, l2c2w, l2c2b, f3, l1w, l1b, l2w, l2b,
                                    out1, e1, e2, out);

    (void)in_sizes; (void)n_in; (void)out_size; (void)ws_size;
}